// Round 5
// baseline (171.541 us; speedup 1.0000x reference)
//
#include <hip/hip_runtime.h>
#include <hip/hip_bf16.h>
#include <math.h>

#define BB 4096
#define NN 128

typedef __attribute__((ext_vector_type(8))) __bf16 bf16x8;
typedef __attribute__((ext_vector_type(4))) __bf16 bf16x4;
typedef __attribute__((ext_vector_type(4))) float f32x4;

// ---- LDS byte offsets ----
constexpr int OFF_XT   = 0;        // bf16 [16][136]  (d_inv ⊙ x)^T       (dead after M1)
constexpr int OFF_W1T  = 4352;     // bf16 [64][40]   W1^T k16..31 zeroed  (dead after M2)
constexpr int OFF_AG1  = 9472;     // bf16 [128][40]  agg1 c16..31 zeroed  (dead after M2)
constexpr int OFF_AG2  = 0;        // bf16 [128][72]  (M3 -> M4)
constexpr int OFF_GEP  = 0;        // f32 [32][64] graph-emb partials (tail)
constexpr int OFF_GP   = 8192;     // f32 [4][64] beta-MLP partials
constexpr int OFF_AP   = 9216;     // f32 [4][32] decay-MLP partials
constexpr int OFF_SCV  = 9728;     // f32 [128] attn scores -> weights
constexpr int OFF_H1T  = 19712;    // bf16 [64][136]  (d_inv ⊙ h1)^T      (dead after M3)
constexpr int OFF_W2T  = 19712;    // bf16 [64][72]   W2^T (post-M3 -> M4)
constexpr int OFF_RS   = 37120;    // f32 [128] raw rowsums
constexpr int OFF_BNS  = 37632;    // f32 [128]
constexpr int OFF_BNB  = 38144;    // f32 [128]
constexpr int OFF_AW   = 38656;    // f32 [64]
constexpr int OFF_NW   = 38912;    // f32 [64]
constexpr int OFF_GEV  = 39168;    // f32 [64]
constexpr int OFF_SCAL = 39424;    // f32 [4]
constexpr int SMEM_BYTES = 39440;

__device__ inline float eluf(float x)      { return x > 0.f ? x : expm1f(x); }
__device__ inline float softplusf(float x) { return (x > 20.f) ? x : log1pf(expf(x)); }

__global__ __launch_bounds__(512, 6)
void agp_kernel(const float* __restrict__ x_str, const float* __restrict__ x_raw,
                const float* __restrict__ adj,   const float* __restrict__ x_cov,
                const float* __restrict__ age,
                const float* __restrict__ gc1_w, const float* __restrict__ gc1_b,
                const float* __restrict__ gc2_w, const float* __restrict__ gc2_b,
                const float* __restrict__ bn_gamma, const float* __restrict__ bn_beta,
                const float* __restrict__ bn_mean,  const float* __restrict__ bn_var,
                const float* __restrict__ attn_w, const float* __restrict__ attn_b,
                const float* __restrict__ na_w,   const float* __restrict__ na_b,
                const float* __restrict__ beta_w1, const float* __restrict__ beta_b1,
                const float* __restrict__ beta_w2, const float* __restrict__ beta_b2,
                const float* __restrict__ af_w1,  const float* __restrict__ af_b1,
                const float* __restrict__ af_w2,  const float* __restrict__ af_b2,
                float* __restrict__ out)
{
    extern __shared__ __align__(16) char smraw[];
    __bf16* XT  = (__bf16*)(smraw + OFF_XT);
    __bf16* W1T = (__bf16*)(smraw + OFF_W1T);
    __bf16* AG1 = (__bf16*)(smraw + OFF_AG1);
    __bf16* AG2 = (__bf16*)(smraw + OFF_AG2);
    __bf16* H1T = (__bf16*)(smraw + OFF_H1T);
    __bf16* W2T = (__bf16*)(smraw + OFF_W2T);
    float* GEp  = (float*)(smraw + OFF_GEP);
    float* GP   = (float*)(smraw + OFF_GP);
    float* AP   = (float*)(smraw + OFF_AP);
    float* SCv  = (float*)(smraw + OFF_SCV);
    float* RS   = (float*)(smraw + OFF_RS);
    float* BNS  = (float*)(smraw + OFF_BNS);
    float* BNB  = (float*)(smraw + OFF_BNB);
    float* AW   = (float*)(smraw + OFF_AW);
    float* NWv  = (float*)(smraw + OFF_NW);
    float* GEv  = (float*)(smraw + OFF_GEV);
    float* SCAL = (float*)(smraw + OFF_SCAL);

    const int b = blockIdx.x;
    const int t = threadIdx.x;
    const int w    = t >> 6;
    const int lane = t & 63;
    const int ll = lane & 15;
    const int lh = lane >> 4;
    const int myrow = 16*w + ll;

    // ---------------- A0: adj -> registers (A-fragment layout); rowsum via MFMA ----------------
    bf16x8 sf[4];
    {
        const float* arow = adj + (size_t)b*NN*NN + (size_t)myrow*NN;
        #pragma unroll
        for (int kt = 0; kt < 4; ++kt) {
            int c0 = kt*32 + 8*lh;
            float4 a  = *reinterpret_cast<const float4*>(arow + c0);
            float4 a2 = *reinterpret_cast<const float4*>(arow + c0 + 4);
            a.x  += (c0+0==myrow)?1.f:0.f; a.y  += (c0+1==myrow)?1.f:0.f;
            a.z  += (c0+2==myrow)?1.f:0.f; a.w  += (c0+3==myrow)?1.f:0.f;
            a2.x += (c0+4==myrow)?1.f:0.f; a2.y += (c0+5==myrow)?1.f:0.f;
            a2.z += (c0+6==myrow)?1.f:0.f; a2.w += (c0+7==myrow)?1.f:0.f;
            bf16x8 s;
            s[0]=(__bf16)a.x;  s[1]=(__bf16)a.y;  s[2]=(__bf16)a.z;  s[3]=(__bf16)a.w;
            s[4]=(__bf16)a2.x; s[5]=(__bf16)a2.y; s[6]=(__bf16)a2.z; s[7]=(__bf16)a2.w;
            sf[kt] = s;
        }
        // rowsum = A_hat @ ones  (matrix pipe is idle; saves 32 VALU adds + 2 shuffles)
        bf16x8 ones;
        #pragma unroll
        for (int i = 0; i < 8; ++i) ones[i] = (__bf16)1.0f;
        f32x4 rsacc = {0.f, 0.f, 0.f, 0.f};
        #pragma unroll
        for (int kt = 0; kt < 4; ++kt)
            rsacc = __builtin_amdgcn_mfma_f32_16x16x32_bf16(sf[kt], ones, rsacc, 0, 0, 0);
        if (ll == 0) {
            #pragma unroll
            for (int r = 0; r < 4; ++r) RS[16*w + 4*lh + r] = rsacc[r];
        }
    }
    float4 xv = reinterpret_cast<const float4*>(x_str + (size_t)b*NN*16)[t];
    for (int idx = t; idx < 1024; idx += 512) {            // W1^T
        int k = idx >> 6, j = idx & 63;
        W1T[j*40 + k] = (__bf16)gc1_w[idx];
    }
    for (int idx = t; idx < 1024; idx += 512) {            // W1^T zero pad k=16..31
        int j = idx >> 4, k = idx & 15;
        W1T[j*40 + 16 + k] = (__bf16)0.f;
    }
    for (int idx = t; idx < 2048; idx += 512) {            // AG1 zero pad c=16..31
        int r = idx >> 4, c = idx & 15;
        AG1[r*40 + 16 + c] = (__bf16)0.f;
    }
    if (t < 128) {
        float g = bn_gamma[t], be = bn_beta[t], mu = bn_mean[t], va = bn_var[t];
        float sc = g * rsqrtf(va + 1e-5f);
        BNS[t] = sc;
        BNB[t] = be - mu*sc;
    } else if (t < 192) {
        AW[t-128] = attn_w[t-128];
    } else if (t < 256) {
        NWv[t-192] = na_w[t-192];
    }
    __syncthreads();   // bar1

    // ---------------- A1: XT = (d_inv ⊙ x)^T ----------------
    {
        int m = t >> 2;
        float dm = rsqrtf(RS[m]);             // rowsum >= 1, never inf
        int c0 = (t & 3) * 4;
        XT[(c0+0)*136 + m] = (__bf16)(xv.x * dm);
        XT[(c0+1)*136 + m] = (__bf16)(xv.y * dm);
        XT[(c0+2)*136 + m] = (__bf16)(xv.z * dm);
        XT[(c0+3)*136 + m] = (__bf16)(xv.w * dm);
    }
    __syncthreads();   // bar2

    // ---------------- M1: agg1 = d_r ⊙ (A_hat @ (d_c ⊙ x)) ----------------
    float dr[4];
    {
        f32x4 acc = {0.f, 0.f, 0.f, 0.f};
        #pragma unroll
        for (int kt = 0; kt < 4; ++kt) {
            bf16x8 bf = *reinterpret_cast<const bf16x8*>(&XT[ll*136 + kt*32 + 8*lh]);
            acc = __builtin_amdgcn_mfma_f32_16x16x32_bf16(sf[kt], bf, acc, 0, 0, 0);
        }
        #pragma unroll
        for (int r = 0; r < 4; ++r) {
            int row = 16*w + 4*lh + r;
            dr[r] = rsqrtf(RS[row]);
            AG1[row*40 + ll] = (__bf16)(acc[r] * dr[r]);
        }
    }
    __syncthreads();   // bar3

    // ---------------- M2: h1 = elu(agg1 @ W1 + b1); H1T = (d_inv ⊙ h1)^T (b64 packed) ----------------
    {
        bf16x8 a = *reinterpret_cast<const bf16x8*>(&AG1[(16*w + ll)*40 + 8*lh]);
        #pragma unroll
        for (int jt = 0; jt < 4; ++jt) {
            bf16x8 bf = *reinterpret_cast<const bf16x8*>(&W1T[(16*jt + ll)*40 + 8*lh]);
            f32x4 z = {0.f, 0.f, 0.f, 0.f};
            f32x4 acc = __builtin_amdgcn_mfma_f32_16x16x32_bf16(a, bf, z, 0, 0, 0);
            float bj = gc1_b[16*jt + ll];
            bf16x4 pk;
            #pragma unroll
            for (int r = 0; r < 4; ++r) {
                float v = eluf(acc[r] + bj);
                pk[r] = (__bf16)(v * dr[r]);
            }
            // rows 16w+4lh+0..3 are consecutive H1T columns -> one aligned b64 write
            *reinterpret_cast<bf16x4*>(&H1T[(16*jt + ll)*136 + 16*w + 4*lh]) = pk;
        }
    }
    __syncthreads();   // bar4

    // ---------------- M3: agg2 = d_r ⊙ (A_hat @ (d_c ⊙ h1)) ----------------
    {
        f32x4 acc2[4];
        #pragma unroll
        for (int jt = 0; jt < 4; ++jt) acc2[jt] = (f32x4){0.f, 0.f, 0.f, 0.f};
        #pragma unroll
        for (int kt = 0; kt < 4; ++kt) {
            #pragma unroll
            for (int jt = 0; jt < 4; ++jt) {
                bf16x8 bf = *reinterpret_cast<const bf16x8*>(&H1T[(16*jt + ll)*136 + kt*32 + 8*lh]);
                acc2[jt] = __builtin_amdgcn_mfma_f32_16x16x32_bf16(sf[kt], bf, acc2[jt], 0, 0, 0);
            }
        }
        #pragma unroll
        for (int jt = 0; jt < 4; ++jt) {
            #pragma unroll
            for (int r = 0; r < 4; ++r) {
                int row = 16*w + 4*lh + r;
                AG2[row*72 + 16*jt + ll] = (__bf16)(acc2[jt][r] * dr[r]);
            }
        }
    }
    // W2 gather -> regs (overlaps barrier wait)
    float w2r[8];
    {
        int j = t >> 3, kb = (t & 7) * 8;
        #pragma unroll
        for (int i = 0; i < 8; ++i) w2r[i] = gc2_w[(kb + i)*64 + j];
    }
    __syncthreads();   // bar5: all H1T reads done
    {
        int j = t >> 3, kb = (t & 7) * 8;
        bf16x8 pv;
        #pragma unroll
        for (int i = 0; i < 8; ++i) pv[i] = (__bf16)w2r[i];
        *reinterpret_cast<bf16x8*>(&W2T[j*72 + kb]) = pv;
    }
    __syncthreads();   // bar6

    // ---------------- M4: h = BN(elu(agg2 @ W2 + b2)) -> stays in registers ----------------
    f32x4 hv[4];
    {
        #pragma unroll
        for (int jt = 0; jt < 4; ++jt) hv[jt] = (f32x4){0.f, 0.f, 0.f, 0.f};
        #pragma unroll
        for (int kt = 0; kt < 2; ++kt) {
            bf16x8 a = *reinterpret_cast<const bf16x8*>(&AG2[(16*w + ll)*72 + kt*32 + 8*lh]);
            #pragma unroll
            for (int jt = 0; jt < 4; ++jt) {
                bf16x8 bf = *reinterpret_cast<const bf16x8*>(&W2T[(16*jt + ll)*72 + kt*32 + 8*lh]);
                hv[jt] = __builtin_amdgcn_mfma_f32_16x16x32_bf16(a, bf, hv[jt], 0, 0, 0);
            }
        }
        float bns[4], bnb_[4];
        #pragma unroll
        for (int r = 0; r < 4; ++r) {
            int row = 16*w + 4*lh + r;
            bns[r] = BNS[row]; bnb_[r] = BNB[row];
        }
        #pragma unroll
        for (int jt = 0; jt < 4; ++jt) {
            float bj = gc2_b[16*jt + ll];
            #pragma unroll
            for (int r = 0; r < 4; ++r)
                hv[jt][r] = eluf(hv[jt][r] + bj) * bns[r] + bnb_[r];
        }
    }
    __syncthreads();   // bar7

    // ---------------- F1: attention scores + alpha_node from registers ----------------
    {
        float aA[4] = {0,0,0,0}, aN[4] = {0,0,0,0};
        #pragma unroll
        for (int jt = 0; jt < 4; ++jt) {
            float wA = AW[16*jt + ll], wN = NWv[16*jt + ll];
            #pragma unroll
            for (int r = 0; r < 4; ++r) {
                aA[r] += hv[jt][r] * wA;
                aN[r] += hv[jt][r] * wN;
            }
        }
        #pragma unroll
        for (int m = 1; m <= 8; m <<= 1) {
            #pragma unroll
            for (int r = 0; r < 4; ++r) {
                aA[r] += __shfl_xor(aA[r], m);
                aN[r] += __shfl_xor(aN[r], m);
            }
        }
        if (ll == 0) {
            float sA = attn_b[0], sN = na_b[0];
            #pragma unroll
            for (int r = 0; r < 4; ++r) {
                int row = 16*w + 4*lh + r;
                SCv[row] = aA[r] + sA;
                out[12288 + (size_t)b*NN + row] = softplusf(aN[r] + sN);   // alpha_node
            }
        }
    }
    __syncthreads();   // bar8

    // ---------------- F2: softmax over nodes (wave 0) ----------------
    if (t < 64) {
        float s0 = SCv[t], s1 = SCv[64 + t];
        float mx = fmaxf(s0, s1);
        #pragma unroll
        for (int m = 32; m >= 1; m >>= 1) mx = fmaxf(mx, __shfl_xor(mx, m));
        float e0 = expf(s0 - mx), e1 = expf(s1 - mx);
        float sum = e0 + e1;
        #pragma unroll
        for (int m = 32; m >= 1; m >>= 1) sum += __shfl_xor(sum, m);
        float inv = 1.f / sum;
        float w0 = e0*inv, w1 = e1*inv;
        SCv[t]      = w0;
        SCv[64 + t] = w1;
        out[536576 + (size_t)b*NN + t]      = w0;          // weights
        out[536576 + (size_t)b*NN + 64 + t] = w1;
    }
    __syncthreads();   // bar9

    // ---------------- F3: graph_emb partials from registers ----------------
    {
        float wt[4];
        #pragma unroll
        for (int r = 0; r < 4; ++r) wt[r] = SCv[16*w + 4*lh + r];
        #pragma unroll
        for (int jt = 0; jt < 4; ++jt) {
            float g = 0.f;
            #pragma unroll
            for (int r = 0; r < 4; ++r) g += hv[jt][r] * wt[r];
            GEp[(4*w + lh)*64 + 16*jt + ll] = g;
        }
    }
    __syncthreads();   // bar10
    if (t < 64) {
        float ge = 0.f;
        #pragma unroll
        for (int g = 0; g < 32; ++g) ge += GEp[g*64 + t];
        GEv[t] = ge;
    }
    __syncthreads();   // bar11

    // ---------------- G1: MLP partials ----------------
    if (t < 256) {
        int c = t >> 6, j = t & 63;
        float p = 0.f;
        for (int i = c*50; i < c*50 + 50; ++i) {
            float v = (i < 128) ? x_raw[(size_t)b*128 + i]
                    : (i < 136) ? x_cov[(size_t)b*8 + (i - 128)]
                                : GEv[i - 136];
            p += v * beta_w1[i*64 + j];
        }
        GP[c*64 + j] = p;
    } else if (t < 384) {
        int u = t - 256, c = u >> 5, j = u & 31;
        float p = 0.f;
        for (int i = c*48; i < c*48 + 48; ++i) {
            float v = (i < 64) ? GEv[i] : x_raw[(size_t)b*128 + (i - 64)];
            p += v * af_w1[i*32 + j];
        }
        AP[c*32 + j] = p;
    }
    __syncthreads();   // bar12

    // ---------------- G2: finish ----------------
    if (t < 64) {
        float acc = beta_b1[t] + GP[t] + GP[64 + t] + GP[128 + t] + GP[192 + t];
        float p = tanhf(acc) * beta_w2[t];
        #pragma unroll
        for (int m = 32; m >= 1; m >>= 1) p += __shfl_xor(p, m);
        if (t == 0) SCAL[0] = 1.f / (1.f + expf(-(p + beta_b2[0])));
    } else if (t < 96) {
        int u = t - 64;
        float acc = af_b1[u] + AP[u] + AP[32 + u] + AP[64 + u] + AP[96 + u];
        float p = fmaxf(acc, 0.f) * af_w2[u];
        #pragma unroll
        for (int m = 16; m >= 1; m >>= 1) p += __shfl_xor(p, m);
        if (u == 0) SCAL[1] = softplusf(p + af_b2[0]);
    }
    __syncthreads();   // bar13

    if (t == 0) {
        float bet = SCAL[0], dec = SCAL[1];
        out[b]        = bet * (1.f - dec * age[b]);   // pred
        out[4096 + b] = bet;                          // beta
        out[8192 + b] = dec;                          // decay_rate
    }
}

extern "C" void kernel_launch(void* const* d_in, const int* in_sizes, int n_in,
                              void* d_out, int out_size, void* d_ws, size_t ws_size,
                              hipStream_t stream) {
    (void)in_sizes; (void)n_in; (void)out_size; (void)d_ws; (void)ws_size;
    const float* x_str   = (const float*)d_in[0];
    const float* x_raw   = (const float*)d_in[1];
    const float* adj     = (const float*)d_in[2];
    const float* x_cov   = (const float*)d_in[3];
    const float* age     = (const float*)d_in[4];
    const float* gc1_w   = (const float*)d_in[5];
    const float* gc1_b   = (const float*)d_in[6];
    const float* gc2_w   = (const float*)d_in[7];
    const float* gc2_b   = (const float*)d_in[8];
    const float* bn_g    = (const float*)d_in[9];
    const float* bn_b    = (const float*)d_in[10];
    const float* bn_m    = (const float*)d_in[11];
    const float* bn_v    = (const float*)d_in[12];
    const float* attn_w  = (const float*)d_in[13];
    const float* attn_b  = (const float*)d_in[14];
    const float* na_w    = (const float*)d_in[15];
    const float* na_b    = (const float*)d_in[16];
    const float* beta_w1 = (const float*)d_in[17];
    const float* beta_b1 = (const float*)d_in[18];
    const float* beta_w2 = (const float*)d_in[19];
    const float* beta_b2 = (const float*)d_in[20];
    const float* af_w1   = (const float*)d_in[21];
    const float* af_b1   = (const float*)d_in[22];
    const float* af_w2   = (const float*)d_in[23];
    const float* af_b2   = (const float*)d_in[24];
    float* out = (float*)d_out;

    (void)hipFuncSetAttribute((const void*)agp_kernel,
                              hipFuncAttributeMaxDynamicSharedMemorySize, SMEM_BYTES);
    agp_kernel<<<BB, 512, SMEM_BYTES, stream>>>(
        x_str, x_raw, adj, x_cov, age,
        gc1_w, gc1_b, gc2_w, gc2_b,
        bn_g, bn_b, bn_m, bn_v,
        attn_w, attn_b, na_w, na_b,
        beta_w1, beta_b1, beta_w2, beta_b2,
        af_w1, af_b1, af_w2, af_b2,
        out);
}

// Round 6
// 155.358 us; speedup vs baseline: 1.1042x; 1.1042x over previous
//
#include <hip/hip_runtime.h>
#include <hip/hip_bf16.h>
#include <math.h>

#define BB 4096
#define NN 128

typedef __attribute__((ext_vector_type(8))) __bf16 bf16x8;
typedef __attribute__((ext_vector_type(4))) __bf16 bf16x4;
typedef __attribute__((ext_vector_type(4))) float f32x4;

// ---- LDS byte offsets ----
// region1 [0,19712): XT+W1T+AG1 -> AG2 [128][72] -> tail GEp/GP/AP
// region2 [19712,37120): H1T -> W2T
// misc    [37120,39440): BNS,BNB,AW,NW,SCv,GEv,SCAL
constexpr int OFF_XT   = 0;        // bf16 [16][136]
constexpr int OFF_W1T  = 4352;     // bf16 [64][40]  (k16..31 zeroed)
constexpr int OFF_AG1  = 9472;     // bf16 [128][40] (c16..31 zeroed)
constexpr int OFF_AG2  = 0;        // bf16 [128][72]
constexpr int OFF_GEP  = 0;        // f32 [32][64]
constexpr int OFF_GP   = 8192;     // f32 [4][64]
constexpr int OFF_AP   = 9216;     // f32 [4][32]
constexpr int OFF_H1T  = 19712;    // bf16 [64][136]
constexpr int OFF_W2T  = 19712;    // bf16 [64][72]
constexpr int OFF_BNS  = 37120;    // f32 [128]
constexpr int OFF_BNB  = 37632;    // f32 [128]
constexpr int OFF_AW   = 38144;    // f32 [64]
constexpr int OFF_NW   = 38400;    // f32 [64]
constexpr int OFF_SCV  = 38656;    // f32 [128]
constexpr int OFF_GEV  = 39168;    // f32 [64]
constexpr int OFF_SCAL = 39424;    // f32 [4]
constexpr int SMEM_BYTES = 39440;  // 4 blocks/CU

__device__ inline float eluf(float x)      { return x > 0.f ? x : expm1f(x); }
__device__ inline float softplusf(float x) { return (x > 20.f) ? x : log1pf(expf(x)); }

__global__ __launch_bounds__(512, 8)
void agp_kernel(const float* __restrict__ x_str, const float* __restrict__ x_raw,
                const float* __restrict__ adj,   const float* __restrict__ x_cov,
                const float* __restrict__ age,
                const float* __restrict__ gc1_w, const float* __restrict__ gc1_b,
                const float* __restrict__ gc2_w, const float* __restrict__ gc2_b,
                const float* __restrict__ bn_gamma, const float* __restrict__ bn_beta,
                const float* __restrict__ bn_mean,  const float* __restrict__ bn_var,
                const float* __restrict__ attn_w, const float* __restrict__ attn_b,
                const float* __restrict__ na_w,   const float* __restrict__ na_b,
                const float* __restrict__ beta_w1, const float* __restrict__ beta_b1,
                const float* __restrict__ beta_w2, const float* __restrict__ beta_b2,
                const float* __restrict__ af_w1,  const float* __restrict__ af_b1,
                const float* __restrict__ af_w2,  const float* __restrict__ af_b2,
                float* __restrict__ out)
{
    extern __shared__ __align__(16) char smraw[];
    __bf16* XT  = (__bf16*)(smraw + OFF_XT);
    __bf16* W1T = (__bf16*)(smraw + OFF_W1T);
    __bf16* AG1 = (__bf16*)(smraw + OFF_AG1);
    __bf16* AG2 = (__bf16*)(smraw + OFF_AG2);
    __bf16* H1T = (__bf16*)(smraw + OFF_H1T);
    __bf16* W2T = (__bf16*)(smraw + OFF_W2T);
    float* GEp  = (float*)(smraw + OFF_GEP);
    float* GP   = (float*)(smraw + OFF_GP);
    float* AP   = (float*)(smraw + OFF_AP);
    float* BNS  = (float*)(smraw + OFF_BNS);
    float* BNB  = (float*)(smraw + OFF_BNB);
    float* AW   = (float*)(smraw + OFF_AW);
    float* NWv  = (float*)(smraw + OFF_NW);
    float* SCv  = (float*)(smraw + OFF_SCV);
    float* GEv  = (float*)(smraw + OFF_GEV);
    float* SCAL = (float*)(smraw + OFF_SCAL);

    const int b = blockIdx.x;
    const int t = threadIdx.x;
    const int w    = t >> 6;
    const int lane = t & 63;
    const int ll = lane & 15;
    const int lh = lane >> 4;
    const int myrow = 16*w + ll;

    // ---------------- A0: adj -> A-fragments + VALU rowsum; stage XT/W1T/misc ----------------
    bf16x8 sf[4];
    float rs = 0.f;
    {
        const float* arow = adj + (size_t)b*NN*NN + (size_t)myrow*NN;
        #pragma unroll
        for (int kt = 0; kt < 4; ++kt) {
            int c0 = kt*32 + 8*lh;
            float4 a  = *reinterpret_cast<const float4*>(arow + c0);
            float4 a2 = *reinterpret_cast<const float4*>(arow + c0 + 4);
            a.x  += (c0+0==myrow)?1.f:0.f; a.y  += (c0+1==myrow)?1.f:0.f;
            a.z  += (c0+2==myrow)?1.f:0.f; a.w  += (c0+3==myrow)?1.f:0.f;
            a2.x += (c0+4==myrow)?1.f:0.f; a2.y += (c0+5==myrow)?1.f:0.f;
            a2.z += (c0+6==myrow)?1.f:0.f; a2.w += (c0+7==myrow)?1.f:0.f;
            rs += ((a.x+a.y)+(a.z+a.w)) + ((a2.x+a2.y)+(a2.z+a2.w));
            bf16x8 s;
            s[0]=(__bf16)a.x;  s[1]=(__bf16)a.y;  s[2]=(__bf16)a.z;  s[3]=(__bf16)a.w;
            s[4]=(__bf16)a2.x; s[5]=(__bf16)a2.y; s[6]=(__bf16)a2.z; s[7]=(__bf16)a2.w;
            sf[kt] = s;
        }
        rs += __shfl_xor(rs, 16);
        rs += __shfl_xor(rs, 32);     // every lane: rowsum of myrow
    }
    {   // XT = (d_inv ⊙ x)^T  — local d_inv, no barrier needed
        float dm = rsqrtf(rs);        // rowsum >= 1, never inf
        float4 xr = *reinterpret_cast<const float4*>(x_str + (size_t)b*NN*16 + myrow*16 + 4*lh);
        XT[(4*lh+0)*136 + myrow] = (__bf16)(xr.x * dm);
        XT[(4*lh+1)*136 + myrow] = (__bf16)(xr.y * dm);
        XT[(4*lh+2)*136 + myrow] = (__bf16)(xr.z * dm);
        XT[(4*lh+3)*136 + myrow] = (__bf16)(xr.w * dm);
    }
    for (int idx = t; idx < 1024; idx += 512) {            // W1^T
        int k = idx >> 6, j = idx & 63;
        W1T[j*40 + k] = (__bf16)gc1_w[idx];
    }
    for (int idx = t; idx < 1024; idx += 512) {            // W1^T zero pad k=16..31
        int j = idx >> 4, k = idx & 15;
        W1T[j*40 + 16 + k] = (__bf16)0.f;
    }
    for (int idx = t; idx < 2048; idx += 512) {            // AG1 zero pad c=16..31
        int r = idx >> 4, c = idx & 15;
        AG1[r*40 + 16 + c] = (__bf16)0.f;
    }
    if (t < 128) {
        float g = bn_gamma[t], be = bn_beta[t], mu = bn_mean[t], va = bn_var[t];
        float sc = g * rsqrtf(va + 1e-5f);
        BNS[t] = sc;
        BNB[t] = be - mu*sc;
    } else if (t < 192) {
        AW[t-128] = attn_w[t-128];
    } else if (t < 256) {
        NWv[t-192] = na_w[t-192];
    }
    __syncthreads();   // b1

    // ---------------- M1: agg1 = d_r ⊙ (A_hat @ (d_c ⊙ x)) ----------------
    float dr[4];
    #pragma unroll
    for (int r = 0; r < 4; ++r) dr[r] = rsqrtf(__shfl(rs, 4*lh + r));
    {
        f32x4 acc = {0.f, 0.f, 0.f, 0.f};
        #pragma unroll
        for (int kt = 0; kt < 4; ++kt) {
            bf16x8 bf = *reinterpret_cast<const bf16x8*>(&XT[ll*136 + kt*32 + 8*lh]);
            acc = __builtin_amdgcn_mfma_f32_16x16x32_bf16(sf[kt], bf, acc, 0, 0, 0);
        }
        #pragma unroll
        for (int r = 0; r < 4; ++r)
            AG1[(16*w + 4*lh + r)*40 + ll] = (__bf16)(acc[r] * dr[r]);
    }
    __syncthreads();   // b2

    // ---------------- M2: h1 = elu(agg1 @ W1 + b1); H1T = (d_inv ⊙ h1)^T ----------------
    {
        bf16x8 a = *reinterpret_cast<const bf16x8*>(&AG1[(16*w + ll)*40 + 8*lh]);
        #pragma unroll
        for (int jt = 0; jt < 4; ++jt) {
            bf16x8 bf = *reinterpret_cast<const bf16x8*>(&W1T[(16*jt + ll)*40 + 8*lh]);
            f32x4 z = {0.f, 0.f, 0.f, 0.f};
            f32x4 acc = __builtin_amdgcn_mfma_f32_16x16x32_bf16(a, bf, z, 0, 0, 0);
            float bj = gc1_b[16*jt + ll];
            bf16x4 pk;
            #pragma unroll
            for (int r = 0; r < 4; ++r) {
                float v = eluf(acc[r] + bj);
                pk[r] = (__bf16)(v * dr[r]);
            }
            *reinterpret_cast<bf16x4*>(&H1T[(16*jt + ll)*136 + 16*w + 4*lh]) = pk;
        }
    }
    __syncthreads();   // b3

    // ---------------- M3: agg2 = d_r ⊙ (A_hat @ (d_c ⊙ h1)) ----------------
    {
        f32x4 acc2[4];
        #pragma unroll
        for (int jt = 0; jt < 4; ++jt) acc2[jt] = (f32x4){0.f, 0.f, 0.f, 0.f};
        #pragma unroll
        for (int kt = 0; kt < 4; ++kt) {
            #pragma unroll
            for (int jt = 0; jt < 4; ++jt) {
                bf16x8 bf = *reinterpret_cast<const bf16x8*>(&H1T[(16*jt + ll)*136 + kt*32 + 8*lh]);
                acc2[jt] = __builtin_amdgcn_mfma_f32_16x16x32_bf16(sf[kt], bf, acc2[jt], 0, 0, 0);
            }
        }
        #pragma unroll
        for (int jt = 0; jt < 4; ++jt) {
            #pragma unroll
            for (int r = 0; r < 4; ++r)
                AG2[(16*w + 4*lh + r)*72 + 16*jt + ll] = (__bf16)(acc2[jt][r] * dr[r]);
        }
    }
    // W2 gather -> regs (overlaps barrier wait)
    float w2r[8];
    {
        int j = t >> 3, kb = (t & 7) * 8;
        #pragma unroll
        for (int i = 0; i < 8; ++i) w2r[i] = gc2_w[(kb + i)*64 + j];
    }
    __syncthreads();   // b4: H1T reads + AG2 writes done
    {
        int j = t >> 3, kb = (t & 7) * 8;
        bf16x8 pv;
        #pragma unroll
        for (int i = 0; i < 8; ++i) pv[i] = (__bf16)w2r[i];
        *reinterpret_cast<bf16x8*>(&W2T[j*72 + kb]) = pv;
    }
    __syncthreads();   // b5

    // ---------------- M4: h = BN(elu(agg2 @ W2 + b2)) in regs; F1: scores ----------------
    f32x4 hv[4];
    {
        #pragma unroll
        for (int jt = 0; jt < 4; ++jt) hv[jt] = (f32x4){0.f, 0.f, 0.f, 0.f};
        #pragma unroll
        for (int kt = 0; kt < 2; ++kt) {
            bf16x8 a = *reinterpret_cast<const bf16x8*>(&AG2[(16*w + ll)*72 + kt*32 + 8*lh]);
            #pragma unroll
            for (int jt = 0; jt < 4; ++jt) {
                bf16x8 bf = *reinterpret_cast<const bf16x8*>(&W2T[(16*jt + ll)*72 + kt*32 + 8*lh]);
                hv[jt] = __builtin_amdgcn_mfma_f32_16x16x32_bf16(a, bf, hv[jt], 0, 0, 0);
            }
        }
        #pragma unroll
        for (int jt = 0; jt < 4; ++jt) {
            float bj = gc2_b[16*jt + ll];
            #pragma unroll
            for (int r = 0; r < 4; ++r) {
                int row = 16*w + 4*lh + r;
                hv[jt][r] = eluf(hv[jt][r] + bj) * BNS[row] + BNB[row];
            }
        }
    }
    // F1: attention + alpha_node scores (no barrier needed: SCv is in misc region)
    float scA[4];
    {
        float aA[4] = {0,0,0,0}, aN[4] = {0,0,0,0};
        #pragma unroll
        for (int jt = 0; jt < 4; ++jt) {
            float wA = AW[16*jt + ll], wN = NWv[16*jt + ll];
            #pragma unroll
            for (int r = 0; r < 4; ++r) {
                aA[r] += hv[jt][r] * wA;
                aN[r] += hv[jt][r] * wN;
            }
        }
        #pragma unroll
        for (int m = 1; m <= 8; m <<= 1) {
            #pragma unroll
            for (int r = 0; r < 4; ++r) {
                aA[r] += __shfl_xor(aA[r], m);
                aN[r] += __shfl_xor(aN[r], m);
            }
        }
        float sA = attn_b[0], sN = na_b[0];
        #pragma unroll
        for (int r = 0; r < 4; ++r) scA[r] = aA[r] + sA;
        if (ll == 0) {
            #pragma unroll
            for (int r = 0; r < 4; ++r) {
                int row = 16*w + 4*lh + r;
                SCv[row] = scA[r];
                out[12288 + (size_t)b*NN + row] = softplusf(aN[r] + sN);   // alpha_node
            }
        }
    }
    __syncthreads();   // b6

    // ---------------- F2+F3: per-wave softmax + graph-emb partials ----------------
    {
        float s0 = SCv[lane], s1 = SCv[64 + lane];
        float mx = fmaxf(s0, s1);
        #pragma unroll
        for (int m = 32; m >= 1; m >>= 1) mx = fmaxf(mx, __shfl_xor(mx, m));
        float e0 = expf(s0 - mx), e1 = expf(s1 - mx);
        float sum = e0 + e1;
        #pragma unroll
        for (int m = 32; m >= 1; m >>= 1) sum += __shfl_xor(sum, m);
        float inv = 1.f / sum;
        float wt[4];
        #pragma unroll
        for (int r = 0; r < 4; ++r) wt[r] = expf(scA[r] - mx) * inv;
        if (ll == 0) {
            #pragma unroll
            for (int r = 0; r < 4; ++r)
                out[536576 + (size_t)b*NN + 16*w + 4*lh + r] = wt[r];      // weights
        }
        #pragma unroll
        for (int jt = 0; jt < 4; ++jt) {
            float g = 0.f;
            #pragma unroll
            for (int r = 0; r < 4; ++r) g += hv[jt][r] * wt[r];
            GEp[(4*w + lh)*64 + 16*jt + ll] = g;
        }
    }
    __syncthreads();   // b7

    if (t < 64) {
        float ge = 0.f;
        #pragma unroll
        for (int g = 0; g < 32; ++g) ge += GEp[g*64 + t];
        GEv[t] = ge;
    }
    __syncthreads();   // b8

    // ---------------- G1: MLP partials ----------------
    if (t < 256) {
        int c = t >> 6, j = t & 63;
        float p = 0.f;
        for (int i = c*50; i < c*50 + 50; ++i) {
            float v = (i < 128) ? x_raw[(size_t)b*128 + i]
                    : (i < 136) ? x_cov[(size_t)b*8 + (i - 128)]
                                : GEv[i - 136];
            p += v * beta_w1[i*64 + j];
        }
        GP[c*64 + j] = p;
    } else if (t < 384) {
        int u = t - 256, c = u >> 5, j = u & 31;
        float p = 0.f;
        for (int i = c*48; i < c*48 + 48; ++i) {
            float v = (i < 64) ? GEv[i] : x_raw[(size_t)b*128 + (i - 64)];
            p += v * af_w1[i*32 + j];
        }
        AP[c*32 + j] = p;
    }
    __syncthreads();   // b9

    // ---------------- G2: finish ----------------
    if (t < 64) {
        float acc = beta_b1[t] + GP[t] + GP[64 + t] + GP[128 + t] + GP[192 + t];
        float p = tanhf(acc) * beta_w2[t];
        #pragma unroll
        for (int m = 32; m >= 1; m >>= 1) p += __shfl_xor(p, m);
        if (t == 0) SCAL[0] = 1.f / (1.f + expf(-(p + beta_b2[0])));
    } else if (t < 96) {
        int u = t - 64;
        float acc = af_b1[u] + AP[u] + AP[32 + u] + AP[64 + u] + AP[96 + u];
        float p = fmaxf(acc, 0.f) * af_w2[u];
        #pragma unroll
        for (int m = 16; m >= 1; m >>= 1) p += __shfl_xor(p, m);
        if (u == 0) SCAL[1] = softplusf(p + af_b2[0]);
    }
    __syncthreads();   // b10

    if (t == 0) {
        float bet = SCAL[0], dec = SCAL[1];
        out[b]        = bet * (1.f - dec * age[b]);   // pred
        out[4096 + b] = bet;                          // beta
        out[8192 + b] = dec;                          // decay_rate
    }
}

extern "C" void kernel_launch(void* const* d_in, const int* in_sizes, int n_in,
                              void* d_out, int out_size, void* d_ws, size_t ws_size,
                              hipStream_t stream) {
    (void)in_sizes; (void)n_in; (void)out_size; (void)d_ws; (void)ws_size;
    const float* x_str   = (const float*)d_in[0];
    const float* x_raw   = (const float*)d_in[1];
    const float* adj     = (const float*)d_in[2];
    const float* x_cov   = (const float*)d_in[3];
    const float* age     = (const float*)d_in[4];
    const float* gc1_w   = (const float*)d_in[5];
    const float* gc1_b   = (const float*)d_in[6];
    const float* gc2_w   = (const float*)d_in[7];
    const float* gc2_b   = (const float*)d_in[8];
    const float* bn_g    = (const float*)d_in[9];
    const float* bn_b    = (const float*)d_in[10];
    const float* bn_m    = (const float*)d_in[11];
    const float* bn_v    = (const float*)d_in[12];
    const float* attn_w  = (const float*)d_in[13];
    const float* attn_b  = (const float*)d_in[14];
    const float* na_w    = (const float*)d_in[15];
    const float* na_b    = (const float*)d_in[16];
    const float* beta_w1 = (const float*)d_in[17];
    const float* beta_b1 = (const float*)d_in[18];
    const float* beta_w2 = (const float*)d_in[19];
    const float* beta_b2 = (const float*)d_in[20];
    const float* af_w1   = (const float*)d_in[21];
    const float* af_b1   = (const float*)d_in[22];
    const float* af_w2   = (const float*)d_in[23];
    const float* af_b2   = (const float*)d_in[24];
    float* out = (float*)d_out;

    (void)hipFuncSetAttribute((const void*)agp_kernel,
                              hipFuncAttributeMaxDynamicSharedMemorySize, SMEM_BYTES);
    agp_kernel<<<BB, 512, SMEM_BYTES, stream>>>(
        x_str, x_raw, adj, x_cov, age,
        gc1_w, gc1_b, gc2_w, gc2_b,
        bn_g, bn_b, bn_m, bn_v,
        attn_w, attn_b, na_w, na_b,
        beta_w1, beta_b1, beta_w2, beta_b2,
        af_w1, af_b1, af_w2, af_b2,
        out);
}

// Round 7
// 123.048 us; speedup vs baseline: 1.3941x; 1.2626x over previous
//
#include <hip/hip_runtime.h>
#include <hip/hip_bf16.h>
#include <math.h>

#define BB 4096
#define NN 128

typedef __attribute__((ext_vector_type(8))) __bf16 bf16x8;
typedef __attribute__((ext_vector_type(4))) __bf16 bf16x4;
typedef __attribute__((ext_vector_type(4))) float f32x4;

// ---- LDS byte offsets ----
// [0,19712):     XT [16][136] + W1T [64][40] + AG1 [128][40]
//                -> post-b2: W2T [64][72] overlays XT+W1T ([0,9216))
//                -> tail: GEp [0,8192) + GP [8192,9216) + AP [9216,9728)
// [19712,38144): H1T [64][136] (17408) -> post-b3: AG2 wave-private [16][72] x8 (18432)
// [38144,40464): misc
constexpr int OFF_XT   = 0;
constexpr int OFF_W1T  = 4352;
constexpr int OFF_AG1  = 9472;
constexpr int OFF_W2T  = 0;
constexpr int OFF_GEP  = 0;
constexpr int OFF_GP   = 8192;
constexpr int OFF_AP   = 9216;
constexpr int OFF_H1T  = 19712;
constexpr int OFF_AG2  = 19712;    // + w*2304
constexpr int OFF_BNS  = 38144;
constexpr int OFF_BNB  = 38656;
constexpr int OFF_AW   = 39168;
constexpr int OFF_NW   = 39424;
constexpr int OFF_SCV  = 39680;
constexpr int OFF_GEV  = 40192;
constexpr int OFF_SCAL = 40448;
constexpr int SMEM_BYTES = 40464;  // rounds to <=40960 -> 4 blocks/CU

__device__ inline float eluf(float x)      { return x > 0.f ? x : __expf(x) - 1.f; }
__device__ inline float softplusf(float x) { return (x > 20.f) ? x : log1pf(__expf(x)); }

__global__ __launch_bounds__(512, 8)
void agp_kernel(const float* __restrict__ x_str, const float* __restrict__ x_raw,
                const float* __restrict__ adj,   const float* __restrict__ x_cov,
                const float* __restrict__ age,
                const float* __restrict__ gc1_w, const float* __restrict__ gc1_b,
                const float* __restrict__ gc2_w, const float* __restrict__ gc2_b,
                const float* __restrict__ bn_gamma, const float* __restrict__ bn_beta,
                const float* __restrict__ bn_mean,  const float* __restrict__ bn_var,
                const float* __restrict__ attn_w, const float* __restrict__ attn_b,
                const float* __restrict__ na_w,   const float* __restrict__ na_b,
                const float* __restrict__ beta_w1, const float* __restrict__ beta_b1,
                const float* __restrict__ beta_w2, const float* __restrict__ beta_b2,
                const float* __restrict__ af_w1,  const float* __restrict__ af_b1,
                const float* __restrict__ af_w2,  const float* __restrict__ af_b2,
                float* __restrict__ out)
{
    extern __shared__ __align__(16) char smraw[];
    __bf16* XT  = (__bf16*)(smraw + OFF_XT);
    __bf16* W1T = (__bf16*)(smraw + OFF_W1T);
    __bf16* AG1 = (__bf16*)(smraw + OFF_AG1);
    __bf16* W2T = (__bf16*)(smraw + OFF_W2T);
    __bf16* H1T = (__bf16*)(smraw + OFF_H1T);
    float* GEp  = (float*)(smraw + OFF_GEP);
    float* GP   = (float*)(smraw + OFF_GP);
    float* AP   = (float*)(smraw + OFF_AP);
    float* BNS  = (float*)(smraw + OFF_BNS);
    float* BNB  = (float*)(smraw + OFF_BNB);
    float* AW   = (float*)(smraw + OFF_AW);
    float* NWv  = (float*)(smraw + OFF_NW);
    float* SCv  = (float*)(smraw + OFF_SCV);
    float* GEv  = (float*)(smraw + OFF_GEV);
    float* SCAL = (float*)(smraw + OFF_SCAL);

    const int b = blockIdx.x;
    const int t = threadIdx.x;
    const int w    = t >> 6;
    const int lane = t & 63;
    const int ll = lane & 15;
    const int lh = lane >> 4;
    const int myrow = 16*w + ll;
    __bf16* AG2w = (__bf16*)(smraw + OFF_AG2) + w*1152;   // [16][72] wave-private

    // ---------------- A0: adj -> A-fragments + rowsum; stage XT/W1T/misc ----------------
    bf16x8 sf[4];
    float rs = 0.f;
    {
        const float* arow = adj + (size_t)b*NN*NN + (size_t)myrow*NN;
        const bool hasd = (((myrow >> 3) & 3) == lh);
        const int  dkt  = myrow >> 5;
        const int  didx = myrow & 7;
        #pragma unroll
        for (int kt = 0; kt < 4; ++kt) {
            int c0 = kt*32 + 8*lh;
            float4 a  = *reinterpret_cast<const float4*>(arow + c0);
            float4 a2 = *reinterpret_cast<const float4*>(arow + c0 + 4);
            if (kt == dkt && hasd) {                  // wave-uniform kt check
                a.x  += (didx==0)?1.f:0.f; a.y  += (didx==1)?1.f:0.f;
                a.z  += (didx==2)?1.f:0.f; a.w  += (didx==3)?1.f:0.f;
                a2.x += (didx==4)?1.f:0.f; a2.y += (didx==5)?1.f:0.f;
                a2.z += (didx==6)?1.f:0.f; a2.w += (didx==7)?1.f:0.f;
            }
            rs += ((a.x+a.y)+(a.z+a.w)) + ((a2.x+a2.y)+(a2.z+a2.w));
            bf16x8 s;
            s[0]=(__bf16)a.x;  s[1]=(__bf16)a.y;  s[2]=(__bf16)a.z;  s[3]=(__bf16)a.w;
            s[4]=(__bf16)a2.x; s[5]=(__bf16)a2.y; s[6]=(__bf16)a2.z; s[7]=(__bf16)a2.w;
            sf[kt] = s;
        }
        rs += __shfl_xor(rs, 16);
        rs += __shfl_xor(rs, 32);     // every lane: rowsum of myrow (incl. diag)
    }
    {   // XT = (d_inv ⊙ x)^T
        float dm = rsqrtf(rs);
        float4 xr = *reinterpret_cast<const float4*>(x_str + (size_t)b*NN*16 + myrow*16 + 4*lh);
        XT[(4*lh+0)*136 + myrow] = (__bf16)(xr.x * dm);
        XT[(4*lh+1)*136 + myrow] = (__bf16)(xr.y * dm);
        XT[(4*lh+2)*136 + myrow] = (__bf16)(xr.z * dm);
        XT[(4*lh+3)*136 + myrow] = (__bf16)(xr.w * dm);
    }
    if (t < 256) {                                    // W1^T stage + pad (vectorized)
        int j = t & 63, k0 = (t >> 6) * 4;
        bf16x4 pk;
        pk[0] = (__bf16)gc1_w[(k0+0)*64 + j];
        pk[1] = (__bf16)gc1_w[(k0+1)*64 + j];
        pk[2] = (__bf16)gc1_w[(k0+2)*64 + j];
        pk[3] = (__bf16)gc1_w[(k0+3)*64 + j];
        *reinterpret_cast<bf16x4*>(&W1T[j*40 + k0]) = pk;
        bf16x4 z4; z4[0]=z4[1]=z4[2]=z4[3]=(__bf16)0.f;
        *reinterpret_cast<bf16x4*>(&W1T[(t>>2)*40 + 16 + (t&3)*4]) = z4;
    }
    {                                                 // AG1 pad c16..31 (vectorized)
        bf16x4 z4; z4[0]=z4[1]=z4[2]=z4[3]=(__bf16)0.f;
        *reinterpret_cast<bf16x4*>(&AG1[(t>>2)*40 + 16 + (t&3)*4]) = z4;
    }
    if (t < 128) {
        float g = bn_gamma[t], be = bn_beta[t], mu = bn_mean[t], va = bn_var[t];
        float sc = g * rsqrtf(va + 1e-5f);
        BNS[t] = sc;
        BNB[t] = be - mu*sc;
    } else if (t < 192) {
        AW[t-128] = attn_w[t-128];
    } else if (t < 256) {
        NWv[t-192] = na_w[t-192];
    }
    __syncthreads();   // b1

    // ---------------- M1: agg1 (AG1 wave-private: no barrier after) ----------------
    float dr[4];
    #pragma unroll
    for (int r = 0; r < 4; ++r) dr[r] = rsqrtf(__shfl(rs, 4*lh + r));
    {
        f32x4 acc = {0.f, 0.f, 0.f, 0.f};
        #pragma unroll
        for (int kt = 0; kt < 4; ++kt) {
            bf16x8 bf = *reinterpret_cast<const bf16x8*>(&XT[ll*136 + kt*32 + 8*lh]);
            acc = __builtin_amdgcn_mfma_f32_16x16x32_bf16(sf[kt], bf, acc, 0, 0, 0);
        }
        #pragma unroll
        for (int r = 0; r < 4; ++r)
            AG1[(16*w + 4*lh + r)*40 + ll] = (__bf16)(acc[r] * dr[r]);
    }
    // no barrier: M2 reads only wave-own AG1 rows (same-wave DS in-order)

    // ---------------- M2: h1 = elu(agg1 @ W1 + b1); H1T = (d_inv ⊙ h1)^T ----------------
    {
        bf16x8 a = *reinterpret_cast<const bf16x8*>(&AG1[(16*w + ll)*40 + 8*lh]);
        #pragma unroll
        for (int jt = 0; jt < 4; ++jt) {
            bf16x8 bf = *reinterpret_cast<const bf16x8*>(&W1T[(16*jt + ll)*40 + 8*lh]);
            f32x4 z = {0.f, 0.f, 0.f, 0.f};
            f32x4 acc = __builtin_amdgcn_mfma_f32_16x16x32_bf16(a, bf, z, 0, 0, 0);
            float bj = gc1_b[16*jt + ll];
            bf16x4 pk;
            #pragma unroll
            for (int r = 0; r < 4; ++r)
                pk[r] = (__bf16)(eluf(acc[r] + bj) * dr[r]);
            *reinterpret_cast<bf16x4*>(&H1T[(16*jt + ll)*136 + 16*w + 4*lh]) = pk;
        }
    }
    __syncthreads();   // b2: H1T visible; XT/W1T/AG1 dead

    // W2 gather (coalesced), latency hidden under M3
    float w2r[8];
    {
        int j = t & 63, k0 = (t >> 6) * 8;
        #pragma unroll
        for (int i = 0; i < 8; ++i) w2r[i] = gc2_w[(k0 + i)*64 + j];
    }

    // ---------------- M3: agg2 = d_r ⊙ (A_hat @ (d_c ⊙ h1)) -> packed regs ----------------
    bf16x4 pk2[4];
    {
        f32x4 acc2[4];
        #pragma unroll
        for (int jt = 0; jt < 4; ++jt) acc2[jt] = (f32x4){0.f, 0.f, 0.f, 0.f};
        #pragma unroll
        for (int kt = 0; kt < 4; ++kt) {
            #pragma unroll
            for (int jt = 0; jt < 4; ++jt) {
                bf16x8 bf = *reinterpret_cast<const bf16x8*>(&H1T[(16*jt + ll)*136 + kt*32 + 8*lh]);
                acc2[jt] = __builtin_amdgcn_mfma_f32_16x16x32_bf16(sf[kt], bf, acc2[jt], 0, 0, 0);
            }
        }
        #pragma unroll
        for (int jt = 0; jt < 4; ++jt)
            #pragma unroll
            for (int r = 0; r < 4; ++r)
                pk2[jt][r] = (__bf16)(acc2[jt][r] * dr[r]);
    }
    // W2T write into dead XT+W1T space (pre-b3)
    {
        int j = t & 63, k0 = (t >> 6) * 8;
        bf16x8 pv;
        #pragma unroll
        for (int i = 0; i < 8; ++i) pv[i] = (__bf16)w2r[i];
        *reinterpret_cast<bf16x8*>(&W2T[j*72 + k0]) = pv;
    }
    __syncthreads();   // b3: all H1T reads done; W2T visible

    // AG2 write (wave-private slab over dead H1T); M4 follows with no barrier
    #pragma unroll
    for (int jt = 0; jt < 4; ++jt)
        #pragma unroll
        for (int r = 0; r < 4; ++r)
            AG2w[(4*lh + r)*72 + 16*jt + ll] = pk2[jt][r];

    // ---------------- M4: h = BN(elu(agg2 @ W2 + b2)) in regs ----------------
    f32x4 hv[4];
    {
        #pragma unroll
        for (int jt = 0; jt < 4; ++jt) hv[jt] = (f32x4){0.f, 0.f, 0.f, 0.f};
        #pragma unroll
        for (int kt = 0; kt < 2; ++kt) {
            bf16x8 a = *reinterpret_cast<const bf16x8*>(&AG2w[ll*72 + kt*32 + 8*lh]);
            #pragma unroll
            for (int jt = 0; jt < 4; ++jt) {
                bf16x8 bf = *reinterpret_cast<const bf16x8*>(&W2T[(16*jt + ll)*72 + kt*32 + 8*lh]);
                hv[jt] = __builtin_amdgcn_mfma_f32_16x16x32_bf16(a, bf, hv[jt], 0, 0, 0);
            }
        }
        #pragma unroll
        for (int jt = 0; jt < 4; ++jt) {
            float bj = gc2_b[16*jt + ll];
            #pragma unroll
            for (int r = 0; r < 4; ++r) {
                int row = 16*w + 4*lh + r;
                hv[jt][r] = eluf(hv[jt][r] + bj) * BNS[row] + BNB[row];
            }
        }
    }

    // ---------------- F1: attention + alpha_node scores ----------------
    float scA[4];
    {
        float aA[4] = {0,0,0,0}, aN[4] = {0,0,0,0};
        #pragma unroll
        for (int jt = 0; jt < 4; ++jt) {
            float wA = AW[16*jt + ll], wN = NWv[16*jt + ll];
            #pragma unroll
            for (int r = 0; r < 4; ++r) {
                aA[r] += hv[jt][r] * wA;
                aN[r] += hv[jt][r] * wN;
            }
        }
        #pragma unroll
        for (int m = 1; m <= 8; m <<= 1) {
            #pragma unroll
            for (int r = 0; r < 4; ++r) {
                aA[r] += __shfl_xor(aA[r], m);
                aN[r] += __shfl_xor(aN[r], m);
            }
        }
        float sA = attn_b[0], sN = na_b[0];
        #pragma unroll
        for (int r = 0; r < 4; ++r) scA[r] = aA[r] + sA;
        if (ll == 0) {
            #pragma unroll
            for (int r = 0; r < 4; ++r) {
                int row = 16*w + 4*lh + r;
                SCv[row] = scA[r];
                out[12288 + (size_t)b*NN + row] = softplusf(aN[r] + sN);   // alpha_node
            }
        }
    }
    __syncthreads();   // b4

    // ---------------- F2+F3: per-wave softmax + graph-emb partials ----------------
    {
        float s0 = SCv[lane], s1 = SCv[64 + lane];
        float mx = fmaxf(s0, s1);
        #pragma unroll
        for (int m = 32; m >= 1; m >>= 1) mx = fmaxf(mx, __shfl_xor(mx, m));
        float e0 = __expf(s0 - mx), e1 = __expf(s1 - mx);
        float sum = e0 + e1;
        #pragma unroll
        for (int m = 32; m >= 1; m >>= 1) sum += __shfl_xor(sum, m);
        float inv = 1.f / sum;
        float wt[4];
        #pragma unroll
        for (int r = 0; r < 4; ++r) wt[r] = __expf(scA[r] - mx) * inv;
        if (ll == 0) {
            #pragma unroll
            for (int r = 0; r < 4; ++r)
                out[536576 + (size_t)b*NN + 16*w + 4*lh + r] = wt[r];      // weights
        }
        #pragma unroll
        for (int jt = 0; jt < 4; ++jt) {
            float g = 0.f;
            #pragma unroll
            for (int r = 0; r < 4; ++r) g += hv[jt][r] * wt[r];
            GEp[(4*w + lh)*64 + 16*jt + ll] = g;
        }
    }
    __syncthreads();   // b5

    if (t < 64) {
        float ge = 0.f;
        #pragma unroll
        for (int g = 0; g < 32; ++g) ge += GEp[g*64 + t];
        GEv[t] = ge;
    }
    __syncthreads();   // b6

    // ---------------- G1: MLP partials ----------------
    if (t < 256) {
        int c = t >> 6, j = t & 63;
        float p = 0.f;
        for (int i = c*50; i < c*50 + 50; ++i) {
            float v = (i < 128) ? x_raw[(size_t)b*128 + i]
                    : (i < 136) ? x_cov[(size_t)b*8 + (i - 128)]
                                : GEv[i - 136];
            p += v * beta_w1[i*64 + j];
        }
        GP[c*64 + j] = p;
    } else if (t < 384) {
        int u = t - 256, c = u >> 5, j = u & 31;
        float p = 0.f;
        for (int i = c*48; i < c*48 + 48; ++i) {
            float v = (i < 64) ? GEv[i] : x_raw[(size_t)b*128 + (i - 64)];
            p += v * af_w1[i*32 + j];
        }
        AP[c*32 + j] = p;
    }
    __syncthreads();   // b7

    // ---------------- G2: finish ----------------
    if (t < 64) {
        float acc = beta_b1[t] + GP[t] + GP[64 + t] + GP[128 + t] + GP[192 + t];
        float p = tanhf(acc) * beta_w2[t];
        #pragma unroll
        for (int m = 32; m >= 1; m >>= 1) p += __shfl_xor(p, m);
        if (t == 0) SCAL[0] = 1.f / (1.f + __expf(-(p + beta_b2[0])));
    } else if (t < 96) {
        int u = t - 64;
        float acc = af_b1[u] + AP[u] + AP[32 + u] + AP[64 + u] + AP[96 + u];
        float p = fmaxf(acc, 0.f) * af_w2[u];
        #pragma unroll
        for (int m = 16; m >= 1; m >>= 1) p += __shfl_xor(p, m);
        if (u == 0) SCAL[1] = softplusf(p + af_b2[0]);
    }
    __syncthreads();   // b8

    if (t == 0) {
        float bet = SCAL[0], dec = SCAL[1];
        out[b]        = bet * (1.f - dec * age[b]);   // pred
        out[4096 + b] = bet;                          // beta
        out[8192 + b] = dec;                          // decay_rate
    }
}

extern "C" void kernel_launch(void* const* d_in, const int* in_sizes, int n_in,
                              void* d_out, int out_size, void* d_ws, size_t ws_size,
                              hipStream_t stream) {
    (void)in_sizes; (void)n_in; (void)out_size; (void)d_ws; (void)ws_size;
    const float* x_str   = (const float*)d_in[0];
    const float* x_raw   = (const float*)d_in[1];
    const float* adj     = (const float*)d_in[2];
    const float* x_cov   = (const float*)d_in[3];
    const float* age     = (const float*)d_in[4];
    const float* gc1_w   = (const float*)d_in[5];
    const float* gc1_b   = (const float*)d_in[6];
    const float* gc2_w   = (const float*)d_in[7];
    const float* gc2_b   = (const float*)d_in[8];
    const float* bn_g    = (const float*)d_in[9];
    const float* bn_b    = (const float*)d_in[10];
    const float* bn_m    = (const float*)d_in[11];
    const float* bn_v    = (const float*)d_in[12];
    const float* attn_w  = (const float*)d_in[13];
    const float* attn_b  = (const float*)d_in[14];
    const float* na_w    = (const float*)d_in[15];
    const float* na_b    = (const float*)d_in[16];
    const float* beta_w1 = (const float*)d_in[17];
    const float* beta_b1 = (const float*)d_in[18];
    const float* beta_w2 = (const float*)d_in[19];
    const float* beta_b2 = (const float*)d_in[20];
    const float* af_w1   = (const float*)d_in[21];
    const float* af_b1   = (const float*)d_in[22];
    const float* af_w2   = (const float*)d_in[23];
    const float* af_b2   = (const float*)d_in[24];
    float* out = (float*)d_out;

    (void)hipFuncSetAttribute((const void*)agp_kernel,
                              hipFuncAttributeMaxDynamicSharedMemorySize, SMEM_BYTES);
    agp_kernel<<<BB, 512, SMEM_BYTES, stream>>>(
        x_str, x_raw, adj, x_cov, age,
        gc1_w, gc1_b, gc2_w, gc2_b,
        bn_g, bn_b, bn_m, bn_v,
        attn_w, attn_b, na_w, na_b,
        beta_w1, beta_b1, beta_w2, beta_b2,
        af_w1, af_b1, af_w2, af_b2,
        out);
}

// Round 8
// 104.099 us; speedup vs baseline: 1.6479x; 1.1820x over previous
//
#include <hip/hip_runtime.h>
#include <hip/hip_bf16.h>
#include <math.h>

#define BB 4096
#define NN 128

typedef __attribute__((ext_vector_type(8))) __bf16 bf16x8;
typedef __attribute__((ext_vector_type(4))) __bf16 bf16x4;
typedef __attribute__((ext_vector_type(4))) float f32x4;

// ---- LDS byte offsets ----
// [0,19712):     XT [16][136] + W1T [64][40] + AG1 [128][40]
//                -> post-b2: W2T [64][72] overlays XT+W1T
//                -> tail (post-b4): GEp [8][64] f32 + GP [8][64] f32 + AP [16][32] f32
// [19712,38144): H1T [64][136] -> post-b3: AG2 wave-private [16][72] x8
// [38144,40464): misc
constexpr int OFF_XT   = 0;
constexpr int OFF_W1T  = 4352;
constexpr int OFF_AG1  = 9472;
constexpr int OFF_W2T  = 0;
constexpr int OFF_GEP  = 0;        // f32 [8][64]
constexpr int OFF_GP   = 2048;     // f32 [8][64]
constexpr int OFF_AP   = 4096;     // f32 [16][32]
constexpr int OFF_H1T  = 19712;
constexpr int OFF_AG2  = 19712;    // + w*2304
constexpr int OFF_BNS  = 38144;
constexpr int OFF_BNB  = 38656;
constexpr int OFF_AW   = 39168;
constexpr int OFF_NW   = 39424;
constexpr int OFF_SCV  = 39680;
constexpr int OFF_GEV  = 40192;
constexpr int OFF_SCAL = 40448;
constexpr int SMEM_BYTES = 40464;  // <=40960 -> 4 blocks/CU

__device__ inline float eluf(float x)      { return x > 0.f ? x : __expf(x) - 1.f; }
__device__ inline float softplusf(float x) { return (x > 20.f) ? x : log1pf(__expf(x)); }

__global__ __launch_bounds__(512, 8)
void agp_kernel(const float* __restrict__ x_str, const float* __restrict__ x_raw,
                const float* __restrict__ adj,   const float* __restrict__ x_cov,
                const float* __restrict__ age,
                const float* __restrict__ gc1_w, const float* __restrict__ gc1_b,
                const float* __restrict__ gc2_w, const float* __restrict__ gc2_b,
                const float* __restrict__ bn_gamma, const float* __restrict__ bn_beta,
                const float* __restrict__ bn_mean,  const float* __restrict__ bn_var,
                const float* __restrict__ attn_w, const float* __restrict__ attn_b,
                const float* __restrict__ na_w,   const float* __restrict__ na_b,
                const float* __restrict__ beta_w1, const float* __restrict__ beta_b1,
                const float* __restrict__ beta_w2, const float* __restrict__ beta_b2,
                const float* __restrict__ af_w1,  const float* __restrict__ af_b1,
                const float* __restrict__ af_w2,  const float* __restrict__ af_b2,
                float* __restrict__ out)
{
    extern __shared__ __align__(16) char smraw[];
    __bf16* XT  = (__bf16*)(smraw + OFF_XT);
    __bf16* W1T = (__bf16*)(smraw + OFF_W1T);
    __bf16* AG1 = (__bf16*)(smraw + OFF_AG1);
    __bf16* W2T = (__bf16*)(smraw + OFF_W2T);
    __bf16* H1T = (__bf16*)(smraw + OFF_H1T);
    float* GEp  = (float*)(smraw + OFF_GEP);
    float* GP   = (float*)(smraw + OFF_GP);
    float* AP   = (float*)(smraw + OFF_AP);
    float* BNS  = (float*)(smraw + OFF_BNS);
    float* BNB  = (float*)(smraw + OFF_BNB);
    float* AW   = (float*)(smraw + OFF_AW);
    float* NWv  = (float*)(smraw + OFF_NW);
    float* SCv  = (float*)(smraw + OFF_SCV);
    float* GEv  = (float*)(smraw + OFF_GEV);
    float* SCAL = (float*)(smraw + OFF_SCAL);

    const int b = blockIdx.x;
    const int t = threadIdx.x;
    const int w    = t >> 6;
    const int lane = t & 63;
    const int ll = lane & 15;
    const int lh = lane >> 4;
    const int myrow = 16*w + ll;
    __bf16* AG2w = (__bf16*)(smraw + OFF_AG2) + w*1152;   // [16][72] wave-private

    // ---------------- A0: adj -> A-fragments; rowsum via MFMA; stage XT/W1T/misc ----------------
    bf16x8 sf[4];
    float dr[4];   // rsqrt(rowsum) for C-rows 16w+4lh+r
    float dm;      // rsqrt(rowsum) for row myrow
    {
        const float* arow = adj + (size_t)b*NN*NN + (size_t)myrow*NN;
        const bool hasd = (((myrow >> 3) & 3) == lh);
        const int  dkt  = myrow >> 5;
        const int  didx = myrow & 7;
        #pragma unroll
        for (int kt = 0; kt < 4; ++kt) {
            int c0 = kt*32 + 8*lh;
            float4 a  = *reinterpret_cast<const float4*>(arow + c0);
            float4 a2 = *reinterpret_cast<const float4*>(arow + c0 + 4);
            if (kt == dkt && hasd) {                  // wave-uniform kt check
                a.x  += (didx==0)?1.f:0.f; a.y  += (didx==1)?1.f:0.f;
                a.z  += (didx==2)?1.f:0.f; a.w  += (didx==3)?1.f:0.f;
                a2.x += (didx==4)?1.f:0.f; a2.y += (didx==5)?1.f:0.f;
                a2.z += (didx==6)?1.f:0.f; a2.w += (didx==7)?1.f:0.f;
            }
            bf16x8 s;
            s[0]=(__bf16)a.x;  s[1]=(__bf16)a.y;  s[2]=(__bf16)a.z;  s[3]=(__bf16)a.w;
            s[4]=(__bf16)a2.x; s[5]=(__bf16)a2.y; s[6]=(__bf16)a2.z; s[7]=(__bf16)a2.w;
            sf[kt] = s;
        }
        // rowsum = A_hat @ ones on the idle matrix pipe (C: row 4lh'+r, any col)
        bf16x8 ones;
        #pragma unroll
        for (int i = 0; i < 8; ++i) ones[i] = (__bf16)1.0f;
        f32x4 rsacc = {0.f, 0.f, 0.f, 0.f};
        #pragma unroll
        for (int kt = 0; kt < 4; ++kt)
            rsacc = __builtin_amdgcn_mfma_f32_16x16x32_bf16(sf[kt], ones, rsacc, 0, 0, 0);
        // dr[r] = rsqrt(RS[16w+4lh+r]): need rsacc[r] from a lane with lh'==lh
        #pragma unroll
        for (int r = 0; r < 4; ++r) dr[r] = rsqrtf(__shfl(rsacc[r], 16*lh));
        // dm = rsqrt(RS[myrow]): rsacc[ll&3] from a lane with lh'==ll>>2
        float tmp[4];
        #pragma unroll
        for (int r = 0; r < 4; ++r) tmp[r] = __shfl(rsacc[r], 16*(ll >> 2));
        float s01 = (ll & 1) ? tmp[1] : tmp[0];
        float s23 = (ll & 1) ? tmp[3] : tmp[2];
        dm = rsqrtf((ll & 2) ? s23 : s01);
    }
    {   // XT = (d_inv ⊙ x)^T
        float4 xr = *reinterpret_cast<const float4*>(x_str + (size_t)b*NN*16 + myrow*16 + 4*lh);
        XT[(4*lh+0)*136 + myrow] = (__bf16)(xr.x * dm);
        XT[(4*lh+1)*136 + myrow] = (__bf16)(xr.y * dm);
        XT[(4*lh+2)*136 + myrow] = (__bf16)(xr.z * dm);
        XT[(4*lh+3)*136 + myrow] = (__bf16)(xr.w * dm);
    }
    if (t < 256) {                                    // W1^T stage + pad (vectorized)
        int j = t & 63, k0 = (t >> 6) * 4;
        bf16x4 pk;
        pk[0] = (__bf16)gc1_w[(k0+0)*64 + j];
        pk[1] = (__bf16)gc1_w[(k0+1)*64 + j];
        pk[2] = (__bf16)gc1_w[(k0+2)*64 + j];
        pk[3] = (__bf16)gc1_w[(k0+3)*64 + j];
        *reinterpret_cast<bf16x4*>(&W1T[j*40 + k0]) = pk;
        bf16x4 z4; z4[0]=z4[1]=z4[2]=z4[3]=(__bf16)0.f;
        *reinterpret_cast<bf16x4*>(&W1T[(t>>2)*40 + 16 + (t&3)*4]) = z4;
    }
    {                                                 // AG1 pad c16..31 (vectorized)
        bf16x4 z4; z4[0]=z4[1]=z4[2]=z4[3]=(__bf16)0.f;
        *reinterpret_cast<bf16x4*>(&AG1[(t>>2)*40 + 16 + (t&3)*4]) = z4;
    }
    if (t < 128) {
        float g = bn_gamma[t], be = bn_beta[t], mu = bn_mean[t], va = bn_var[t];
        float sc = g * rsqrtf(va + 1e-5f);
        BNS[t] = sc;
        BNB[t] = be - mu*sc;
    } else if (t < 192) {
        AW[t-128] = attn_w[t-128];
    } else if (t < 256) {
        NWv[t-192] = na_w[t-192];
    }
    __syncthreads();   // b1

    // ---------------- M1: agg1 (AG1 wave-private: no barrier after) ----------------
    {
        f32x4 acc = {0.f, 0.f, 0.f, 0.f};
        #pragma unroll
        for (int kt = 0; kt < 4; ++kt) {
            bf16x8 bf = *reinterpret_cast<const bf16x8*>(&XT[ll*136 + kt*32 + 8*lh]);
            acc = __builtin_amdgcn_mfma_f32_16x16x32_bf16(sf[kt], bf, acc, 0, 0, 0);
        }
        #pragma unroll
        for (int r = 0; r < 4; ++r)
            AG1[(16*w + 4*lh + r)*40 + ll] = (__bf16)(acc[r] * dr[r]);
    }
    // no barrier: M2 reads only wave-own AG1 rows (same-wave DS in-order)

    // ---------------- M2: h1 = elu(agg1 @ W1 + b1); H1T = (d_inv ⊙ h1)^T ----------------
    {
        bf16x8 a = *reinterpret_cast<const bf16x8*>(&AG1[(16*w + ll)*40 + 8*lh]);
        #pragma unroll
        for (int jt = 0; jt < 4; ++jt) {
            bf16x8 bf = *reinterpret_cast<const bf16x8*>(&W1T[(16*jt + ll)*40 + 8*lh]);
            f32x4 z = {0.f, 0.f, 0.f, 0.f};
            f32x4 acc = __builtin_amdgcn_mfma_f32_16x16x32_bf16(a, bf, z, 0, 0, 0);
            float bj = gc1_b[16*jt + ll];
            bf16x4 pk;
            #pragma unroll
            for (int r = 0; r < 4; ++r)
                pk[r] = (__bf16)(eluf(acc[r] + bj) * dr[r]);
            *reinterpret_cast<bf16x4*>(&H1T[(16*jt + ll)*136 + 16*w + 4*lh]) = pk;
        }
    }
    __syncthreads();   // b2: H1T visible; XT/W1T/AG1 dead

    // W2 gather (coalesced), latency hidden under M3
    float w2r[8];
    {
        int j = t & 63, k0 = (t >> 6) * 8;
        #pragma unroll
        for (int i = 0; i < 8; ++i) w2r[i] = gc2_w[(k0 + i)*64 + j];
    }

    // ---------------- M3: agg2 = d_r ⊙ (A_hat @ (d_c ⊙ h1)) -> packed regs ----------------
    bf16x4 pk2[4];
    {
        f32x4 acc2[4];
        #pragma unroll
        for (int jt = 0; jt < 4; ++jt) acc2[jt] = (f32x4){0.f, 0.f, 0.f, 0.f};
        #pragma unroll
        for (int kt = 0; kt < 4; ++kt) {
            #pragma unroll
            for (int jt = 0; jt < 4; ++jt) {
                bf16x8 bf = *reinterpret_cast<const bf16x8*>(&H1T[(16*jt + ll)*136 + kt*32 + 8*lh]);
                acc2[jt] = __builtin_amdgcn_mfma_f32_16x16x32_bf16(sf[kt], bf, acc2[jt], 0, 0, 0);
            }
        }
        #pragma unroll
        for (int jt = 0; jt < 4; ++jt)
            #pragma unroll
            for (int r = 0; r < 4; ++r)
                pk2[jt][r] = (__bf16)(acc2[jt][r] * dr[r]);
    }
    // W2T write into dead XT+W1T space (pre-b3)
    {
        int j = t & 63, k0 = (t >> 6) * 8;
        bf16x8 pv;
        #pragma unroll
        for (int i = 0; i < 8; ++i) pv[i] = (__bf16)w2r[i];
        *reinterpret_cast<bf16x8*>(&W2T[j*72 + k0]) = pv;
    }
    __syncthreads();   // b3: all H1T reads done; W2T visible

    // AG2 write (wave-private slab over dead H1T); M4 follows with no barrier
    #pragma unroll
    for (int jt = 0; jt < 4; ++jt)
        #pragma unroll
        for (int r = 0; r < 4; ++r)
            AG2w[(4*lh + r)*72 + 16*jt + ll] = pk2[jt][r];

    // ---------------- M4: h = BN(elu(agg2 @ W2 + b2)) in regs ----------------
    f32x4 hv[4];
    {
        #pragma unroll
        for (int jt = 0; jt < 4; ++jt) hv[jt] = (f32x4){0.f, 0.f, 0.f, 0.f};
        #pragma unroll
        for (int kt = 0; kt < 2; ++kt) {
            bf16x8 a = *reinterpret_cast<const bf16x8*>(&AG2w[ll*72 + kt*32 + 8*lh]);
            #pragma unroll
            for (int jt = 0; jt < 4; ++jt) {
                bf16x8 bf = *reinterpret_cast<const bf16x8*>(&W2T[(16*jt + ll)*72 + kt*32 + 8*lh]);
                hv[jt] = __builtin_amdgcn_mfma_f32_16x16x32_bf16(a, bf, hv[jt], 0, 0, 0);
            }
        }
        #pragma unroll
        for (int jt = 0; jt < 4; ++jt) {
            float bj = gc2_b[16*jt + ll];
            #pragma unroll
            for (int r = 0; r < 4; ++r) {
                int row = 16*w + 4*lh + r;
                hv[jt][r] = eluf(hv[jt][r] + bj) * BNS[row] + BNB[row];
            }
        }
    }

    // ---------------- F1: attention + alpha_node scores ----------------
    float scA[4];
    {
        float aA[4] = {0,0,0,0}, aN[4] = {0,0,0,0};
        #pragma unroll
        for (int jt = 0; jt < 4; ++jt) {
            float wA = AW[16*jt + ll], wN = NWv[16*jt + ll];
            #pragma unroll
            for (int r = 0; r < 4; ++r) {
                aA[r] += hv[jt][r] * wA;
                aN[r] += hv[jt][r] * wN;
            }
        }
        #pragma unroll
        for (int m = 1; m <= 8; m <<= 1) {
            #pragma unroll
            for (int r = 0; r < 4; ++r) {
                aA[r] += __shfl_xor(aA[r], m);
                aN[r] += __shfl_xor(aN[r], m);
            }
        }
        float sA = attn_b[0], sN = na_b[0];
        #pragma unroll
        for (int r = 0; r < 4; ++r) scA[r] = aA[r] + sA;
        if (ll == 0) {
            float4 an4;
            an4.x = softplusf(aN[0] + sN); an4.y = softplusf(aN[1] + sN);
            an4.z = softplusf(aN[2] + sN); an4.w = softplusf(aN[3] + sN);
            #pragma unroll
            for (int r = 0; r < 4; ++r) SCv[16*w + 4*lh + r] = scA[r];
            *reinterpret_cast<float4*>(&out[12288 + (size_t)b*NN + 16*w + 4*lh]) = an4;  // alpha_node
        }
    }
    __syncthreads();   // b4

    // ---------------- F2+F3: per-wave softmax + wave-reduced graph-emb partials ----------------
    {
        float s0 = SCv[lane], s1 = SCv[64 + lane];
        float mx = fmaxf(s0, s1);
        #pragma unroll
        for (int m = 32; m >= 1; m >>= 1) mx = fmaxf(mx, __shfl_xor(mx, m));
        float e0 = __expf(s0 - mx), e1 = __expf(s1 - mx);
        float sum = e0 + e1;
        #pragma unroll
        for (int m = 32; m >= 1; m >>= 1) sum += __shfl_xor(sum, m);
        float inv = 1.f / sum;
        float wt[4];
        #pragma unroll
        for (int r = 0; r < 4; ++r) wt[r] = __expf(scA[r] - mx) * inv;
        if (ll == 0) {
            float4 w4; w4.x = wt[0]; w4.y = wt[1]; w4.z = wt[2]; w4.w = wt[3];
            *reinterpret_cast<float4*>(&out[536576 + (size_t)b*NN + 16*w + 4*lh]) = w4;  // weights
        }
        float gg[4];
        #pragma unroll
        for (int jt = 0; jt < 4; ++jt) {
            float g = 0.f;
            #pragma unroll
            for (int r = 0; r < 4; ++r) g += hv[jt][r] * wt[r];
            g += __shfl_xor(g, 16);
            g += __shfl_xor(g, 32);          // wave-total for col 16jt+ll
            gg[jt] = g;
        }
        float s01 = (lh & 1) ? gg[1] : gg[0];
        float s23 = (lh & 1) ? gg[3] : gg[2];
        GEp[w*64 + lane] = (lh & 2) ? s23 : s01;   // col 16*lh + ll == lane
    }
    __syncthreads();   // b5

    if (t < 64) {
        float ge = 0.f;
        #pragma unroll
        for (int g = 0; g < 8; ++g) ge += GEp[g*64 + t];
        GEv[t] = ge;
    }
    __syncthreads();   // b6

    // ---------------- G1: MLP partials, all 512 threads, wave-uniform chunks ----------------
    {
        // beta_w1 partials: 8 chunks x 25 inputs, outputs j = t&63
        const float* xr = x_raw + (size_t)b*128;
        int j = t & 63;
        float p = 0.f;
        if (w < 5) {
            const float* bw = beta_w1 + (size_t)(w*25)*64 + j;
            const float* xx = xr + w*25;
            #pragma unroll
            for (int k = 0; k < 25; ++k) p += xx[k] * bw[k*64];
        } else if (w == 5) {
            const float* cv = x_cov + (size_t)b*8;
            #pragma unroll
            for (int k = 0; k < 3; ++k)  p += xr[125+k] * beta_w1[(125+k)*64 + j];
            #pragma unroll
            for (int k = 0; k < 8; ++k)  p += cv[k]     * beta_w1[(128+k)*64 + j];
            #pragma unroll
            for (int k = 0; k < 14; ++k) p += GEv[k]    * beta_w1[(136+k)*64 + j];
        } else if (w == 6) {
            #pragma unroll
            for (int k = 0; k < 25; ++k) p += GEv[14+k] * beta_w1[(150+k)*64 + j];
        } else {
            #pragma unroll
            for (int k = 0; k < 25; ++k) p += GEv[39+k] * beta_w1[(175+k)*64 + j];
        }
        GP[w*64 + j] = p;

        // af_w1 partials: 16 chunks x 12 inputs, outputs j2 = t&31
        int j2 = t & 31, ch = t >> 5;
        float q = 0.f;
        if (ch < 5) {
            int i0 = ch*12;
            #pragma unroll
            for (int k = 0; k < 12; ++k) q += GEv[i0+k] * af_w1[(i0+k)*32 + j2];
        } else if (ch == 5) {
            #pragma unroll
            for (int k = 0; k < 4; ++k) q += GEv[60+k] * af_w1[(60+k)*32 + j2];
            #pragma unroll
            for (int k = 0; k < 8; ++k) q += xr[k]     * af_w1[(64+k)*32 + j2];
        } else {
            int i0 = ch*12 - 64;    // 8..127
            #pragma unroll
            for (int k = 0; k < 12; ++k) q += xr[i0+k] * af_w1[(i0+k+64)*32 + j2];
        }
        AP[ch*32 + j2] = q;
    }
    __syncthreads();   // b7

    // ---------------- G2: finish ----------------
    if (t < 64) {
        float acc = beta_b1[t];
        #pragma unroll
        for (int c = 0; c < 8; ++c) acc += GP[c*64 + t];
        float p = tanhf(acc) * beta_w2[t];
        #pragma unroll
        for (int m = 32; m >= 1; m >>= 1) p += __shfl_xor(p, m);
        if (t == 0) SCAL[0] = 1.f / (1.f + __expf(-(p + beta_b2[0])));
    } else if (t < 96) {
        int u = t - 64;
        float acc = af_b1[u];
        #pragma unroll
        for (int c = 0; c < 16; ++c) acc += AP[c*32 + u];
        float p = fmaxf(acc, 0.f) * af_w2[u];
        #pragma unroll
        for (int m = 16; m >= 1; m >>= 1) p += __shfl_xor(p, m);
        if (u == 0) SCAL[1] = softplusf(p + af_b2[0]);
    }
    __syncthreads();   // b8

    if (t == 0) {
        float bet = SCAL[0], dec = SCAL[1];
        out[b]        = bet * (1.f - dec * age[b]);   // pred
        out[4096 + b] = bet;                          // beta
        out[8192 + b] = dec;                          // decay_rate
    }
}

extern "C" void kernel_launch(void* const* d_in, const int* in_sizes, int n_in,
                              void* d_out, int out_size, void* d_ws, size_t ws_size,
                              hipStream_t stream) {
    (void)in_sizes; (void)n_in; (void)out_size; (void)d_ws; (void)ws_size;
    const float* x_str   = (const float*)d_in[0];
    const float* x_raw   = (const float*)d_in[1];
    const float* adj     = (const float*)d_in[2];
    const float* x_cov   = (const float*)d_in[3];
    const float* age     = (const float*)d_in[4];
    const float* gc1_w   = (const float*)d_in[5];
    const float* gc1_b   = (const float*)d_in[6];
    const float* gc2_w   = (const float*)d_in[7];
    const float* gc2_b   = (const float*)d_in[8];
    const float* bn_g    = (const float*)d_in[9];
    const float* bn_b    = (const float*)d_in[10];
    const float* bn_m    = (const float*)d_in[11];
    const float* bn_v    = (const float*)d_in[12];
    const float* attn_w  = (const float*)d_in[13];
    const float* attn_b  = (const float*)d_in[14];
    const float* na_w    = (const float*)d_in[15];
    const float* na_b    = (const float*)d_in[16];
    const float* beta_w1 = (const float*)d_in[17];
    const float* beta_b1 = (const float*)d_in[18];
    const float* beta_w2 = (const float*)d_in[19];
    const float* beta_b2 = (const float*)d_in[20];
    const float* af_w1   = (const float*)d_in[21];
    const float* af_b1   = (const float*)d_in[22];
    const float* af_w2   = (const float*)d_in[23];
    const float* af_b2   = (const float*)d_in[24];
    float* out = (float*)d_out;

    (void)hipFuncSetAttribute((const void*)agp_kernel,
                              hipFuncAttributeMaxDynamicSharedMemorySize, SMEM_BYTES);
    agp_kernel<<<BB, 512, SMEM_BYTES, stream>>>(
        x_str, x_raw, adj, x_cov, age,
        gc1_w, gc1_b, gc2_w, gc2_b,
        bn_g, bn_b, bn_m, bn_v,
        attn_w, attn_b, na_w, na_b,
        beta_w1, beta_b1, beta_w2, beta_b2,
        af_w1, af_b1, af_w2, af_b2,
        out);
}